// Round 2
// baseline (332.184 us; speedup 1.0000x reference)
//
#include <hip/hip_runtime.h>
#include <math.h>

#define NB      512
#define NELEC   30
#define NATOMS  10
#define NNEN    40      // en graph nodes: 30 electrons + 10 atoms
#define FEAT    64
#define KRBF    64
#define BLOCK   512
#define NWAVES  (BLOCK/64)
#define NPEE    435     // unique elec-elec pairs
#define NPEN    300     // unique elec-nuc pairs
#define TILE    32      // feature tile for filt LDS round-trip
#define TPAD    33      // tile row stride (+1 float): banks (p+ff)%32, 2-way = free

// ---------------- LDS layouts (in floats) ----------------
// ee: xyz[96] | h[30*64] | agg[30*64] | fT[435*33]
#define EE_H     96
#define EE_AGG   (EE_H + NELEC*FEAT)
#define EE_FT    (EE_AGG + NELEC*FEAT)
#define EE_TOTAL (EE_FT + NPEE*TPAD)            // 18291 floats = 73164 B -> 2 blocks/CU
// en: xyz[96] | h[40*64] | agg[40*64] | fT[300*33]
#define EN_H     96
#define EN_AGG   (EN_H + NNEN*FEAT)
#define EN_FT    (EN_AGG + NNEN*FEAT)
#define EN_TOTAL (EN_FT + NPEN*TPAD)            // 15116 floats = 60464 B -> 2 blocks/CU

// triangular pair index base for row i (i<j pairs of 30 electrons)
__device__ __forceinline__ int ee_base(int i) { return 29*i - ((i*(i-1))>>1); }

// ==========================================================================
// elec-elec GNN: one block per batch. Writes partial log-Jastrow (double).
// Filter values live in registers (facc[64] per pair-lane) and are staged
// to LDS in 32-feature tiles for the message phase. All FP op sequences are
// bit-identical to the round-1 passing kernel.
// ==========================================================================
__global__ __launch_bounds__(BLOCK, 4)
void ee_kernel(const float* __restrict__ pos,
               const float* __restrict__ emb,
               const float* __restrict__ wf,
               const float* __restrict__ bf,
               const float* __restrict__ wl,
               const float* __restrict__ bl,
               const float* __restrict__ wr,
               const float* __restrict__ br,
               const int*   __restrict__ types,
               double*      __restrict__ kout)
{
    extern __shared__ float sm[];
    float* xyz  = sm;           // [96]
    float* hS   = sm + EE_H;    // [30][64]
    float* aggS = sm + EE_AGG;  // [30][64]
    float* fT   = sm + EE_FT;   // [435][33] feature tile

    const int tid  = threadIdx.x;
    const int b    = blockIdx.x;
    const int lane = tid & 63;
    const int w    = tid >> 6;

    // stage positions; init h = emb[types]
    for (int idx = tid; idx < NELEC*3; idx += BLOCK) xyz[idx] = pos[b*NELEC*3 + idx];
    for (int idx = tid; idx < NELEC*FEAT; idx += BLOCK) {
        int n = idx >> 6, f = idx & 63;
        hS[idx] = emb[types[n]*FEAT + f];
    }
    __syncthreads();

    // ---- filter GEMM: one unique pair per lane (clamped -> uniform CF) ----
    // result (post-tanh) persists in facc[64] registers for both layers
    const int p = (tid < NPEE) ? tid : (NPEE - 1);
    float facc[FEAT];
    {
        int i = 0, rem = p;
        while (rem >= NELEC - 1 - i) { rem -= NELEC - 1 - i; ++i; }
        const int j = i + 1 + rem;
        const float dx = xyz[3*i+0] - xyz[3*j+0];
        const float dy = xyz[3*i+1] - xyz[3*j+1];
        const float dz = xyz[3*i+2] - xyz[3*j+2];
        const float dd = sqrtf(dx*dx + dy*dy + dz*dz);

        #pragma unroll
        for (int f = 0; f < FEAT; ++f) facc[f] = bf[f];  // uniform -> s_load
        #pragma unroll 2
        for (int k = 0; k < KRBF; ++k) {
            const float ck = (float)((double)k * (8.0/63.0));
            const float t  = dd - ck;
            const float rk = expf(-t*t);
            const float* wrow = wf + k*FEAT;             // wave-uniform row
            #pragma unroll
            for (int f = 0; f < FEAT; ++f) facc[f] = fmaf(rk, wrow[f], facc[f]);
        }
        #pragma unroll
        for (int f = 0; f < FEAT; ++f) facc[f] = tanhf(facc[f]);
    }

    // ---- interaction layers ----
    for (int l = 0; l < 2; ++l) {
        const float* wlL = wl + l*FEAT*FEAT;
        const float* blL = bl + l*FEAT;

        // messages, two 32-feature tiles: regs -> LDS tile -> (node,feat) threads
        for (int t = 0; t < 2; ++t) {
            __syncthreads();   // protect fT from previous tile's readers
            #pragma unroll
            for (int ff = 0; ff < TILE; ++ff)
                fT[p*TPAD + ff] = facc[t*TILE + ff];     // dup lanes: same bits, benign
            __syncthreads();

            // agg[i][t*32+ff] = sum_{j!=i, j asc} h[j][f] * filt[p(i,j)][f]
            #pragma unroll
            for (int pass = 0; pass < 2; ++pass) {
                const int idx = tid + pass*BLOCK;
                if (idx < NELEC*TILE) {
                    const int i  = idx >> 5;
                    const int ff = idx & 31;
                    const int f  = t*TILE + ff;
                    float a = 0.f;
                    #pragma unroll
                    for (int j = 0; j < NELEC; ++j) {
                        if (j != i) {
                            int pp = (j < i) ? (ee_base(j) + (i - j - 1))
                                             : (ee_base(i) + (j - i - 1));
                            a = fmaf(hS[j*FEAT + f], fT[pp*TPAD + ff], a);
                        }
                    }
                    aggS[i*FEAT + f] = a;
                }
            }
        }
        __syncthreads();

        // h += tanh(agg @ wl + bl)   (lane = feature, wave-strided nodes)
        for (int i = w; i < NELEC; i += NWAVES) {
            float a2 = 0.f;
            const float4* arow = reinterpret_cast<const float4*>(aggS + i*FEAT);
            #pragma unroll
            for (int k = 0; k < FEAT/4; ++k) {
                float4 av = arow[k];                      // broadcast b128
                a2 = fmaf(av.x, wlL[(4*k+0)*FEAT + lane], a2);
                a2 = fmaf(av.y, wlL[(4*k+1)*FEAT + lane], a2);
                a2 = fmaf(av.z, wlL[(4*k+2)*FEAT + lane], a2);
                a2 = fmaf(av.w, wlL[(4*k+3)*FEAT + lane], a2);
            }
            hS[i*FEAT + lane] += tanhf(a2 + blL[lane]);
        }
        __syncthreads();
    }

    // ---- readout: (sum_n h[n]) . wr + br   (f64 tail) ----
    if (w == 0) {
        float s = 0.f;
        #pragma unroll
        for (int n = 0; n < NELEC; ++n) s += hS[n*FEAT + lane];
        double dv = (double)s * (double)wr[lane];
        #pragma unroll
        for (int o = 32; o > 0; o >>= 1) dv += __shfl_xor(dv, o, 64);
        if (lane == 0) kout[b] = dv + (double)br[0];
    }
}

// ==========================================================================
// elec-nuc GNN + final combine: out[b] = exp(k_ee + k_en)
// ==========================================================================
__global__ __launch_bounds__(BLOCK, 4)
void en_kernel(const float* __restrict__ pos,
               const float* __restrict__ atoms,
               const float* __restrict__ emb,
               const float* __restrict__ wf,
               const float* __restrict__ bf,
               const float* __restrict__ wl,
               const float* __restrict__ bl,
               const float* __restrict__ wr,
               const float* __restrict__ br,
               const int*   __restrict__ types,
               const double* __restrict__ kin,
               float*       __restrict__ out)
{
    extern __shared__ float sm[];
    float* xyz  = sm;           // [96]
    float* hS   = sm + EN_H;    // [40][64]
    float* aggS = sm + EN_AGG;  // [40][64]
    float* fT   = sm + EN_FT;   // [300][33]

    const int tid  = threadIdx.x;
    const int b    = blockIdx.x;
    const int lane = tid & 63;
    const int w    = tid >> 6;

    for (int idx = tid; idx < NELEC*3; idx += BLOCK) xyz[idx] = pos[b*NELEC*3 + idx];
    for (int idx = tid; idx < NNEN*FEAT; idx += BLOCK) {
        int n = idx >> 6, f = idx & 63;
        hS[idx] = emb[types[n]*FEAT + f];
    }
    __syncthreads();

    // ---- filter GEMM: pair q = a*30 + e (atom-major, matches ref ordering) ----
    const int p = (tid < NPEN) ? tid : (NPEN - 1);
    float facc[FEAT];
    {
        const int a = p / NELEC;
        const int e = p - a*NELEC;
        const float dx = xyz[3*e+0] - atoms[3*a+0];
        const float dy = xyz[3*e+1] - atoms[3*a+1];
        const float dz = xyz[3*e+2] - atoms[3*a+2];
        const float dd = sqrtf(dx*dx + dy*dy + dz*dz);

        #pragma unroll
        for (int f = 0; f < FEAT; ++f) facc[f] = bf[f];
        #pragma unroll 2
        for (int k = 0; k < KRBF; ++k) {
            const float ck = (float)((double)k * (8.0/63.0));
            const float t  = dd - ck;
            const float rk = expf(-t*t);
            const float* wrow = wf + k*FEAT;
            #pragma unroll
            for (int f = 0; f < FEAT; ++f) facc[f] = fmaf(rk, wrow[f], facc[f]);
        }
        #pragma unroll
        for (int f = 0; f < FEAT; ++f) facc[f] = tanhf(facc[f]);
    }

    for (int l = 0; l < 2; ++l) {
        const float* wlL = wl + l*FEAT*FEAT;
        const float* blL = bl + l*FEAT;

        for (int t = 0; t < 2; ++t) {
            __syncthreads();
            #pragma unroll
            for (int ff = 0; ff < TILE; ++ff)
                fT[p*TPAD + ff] = facc[t*TILE + ff];
            __syncthreads();

            // bipartite messages: 40 nodes x 32 feats = 1280 items, 3 passes
            #pragma unroll
            for (int pass = 0; pass < 3; ++pass) {
                const int idx = tid + pass*BLOCK;
                if (idx < NNEN*TILE) {
                    const int n  = idx >> 5;
                    const int ff = idx & 31;
                    const int f  = t*TILE + ff;
                    float a = 0.f;
                    if (n < NELEC) {            // electron node: atoms ascending
                        #pragma unroll
                        for (int at = 0; at < NATOMS; ++at)
                            a = fmaf(hS[(NELEC+at)*FEAT + f],
                                     fT[(at*NELEC + n)*TPAD + ff], a);
                    } else {                    // atom node: electrons ascending
                        const int at = n - NELEC;
                        #pragma unroll
                        for (int e2 = 0; e2 < NELEC; ++e2)
                            a = fmaf(hS[e2*FEAT + f],
                                     fT[(at*NELEC + e2)*TPAD + ff], a);
                    }
                    aggS[n*FEAT + f] = a;
                }
            }
        }
        __syncthreads();

        for (int n = w; n < NNEN; n += NWAVES) {
            float a2 = 0.f;
            const float4* arow = reinterpret_cast<const float4*>(aggS + n*FEAT);
            #pragma unroll
            for (int k = 0; k < FEAT/4; ++k) {
                float4 av = arow[k];
                a2 = fmaf(av.x, wlL[(4*k+0)*FEAT + lane], a2);
                a2 = fmaf(av.y, wlL[(4*k+1)*FEAT + lane], a2);
                a2 = fmaf(av.z, wlL[(4*k+2)*FEAT + lane], a2);
                a2 = fmaf(av.w, wlL[(4*k+3)*FEAT + lane], a2);
            }
            hS[n*FEAT + lane] += tanhf(a2 + blL[lane]);
        }
        __syncthreads();
    }

    if (w == 0) {
        float s = 0.f;
        #pragma unroll
        for (int n = 0; n < NNEN; ++n) s += hS[n*FEAT + lane];
        double dv = (double)s * (double)wr[lane];
        #pragma unroll
        for (int o = 32; o > 0; o >>= 1) dv += __shfl_xor(dv, o, 64);
        if (lane == 0) out[b] = (float)exp(dv + (double)br[0] + kin[b]);
    }
}

// ==========================================================================
extern "C" void kernel_launch(void* const* d_in, const int* in_sizes, int n_in,
                              void* d_out, int out_size, void* d_ws, size_t ws_size,
                              hipStream_t stream) {
    const float* pos    = (const float*)d_in[0];
    const float* atoms  = (const float*)d_in[1];
    const float* emb_ee = (const float*)d_in[2];
    const float* wf_ee  = (const float*)d_in[3];
    const float* bf_ee  = (const float*)d_in[4];
    const float* wl_ee  = (const float*)d_in[5];
    const float* bl_ee  = (const float*)d_in[6];
    const float* wr_ee  = (const float*)d_in[7];
    const float* br_ee  = (const float*)d_in[8];
    const float* emb_en = (const float*)d_in[9];
    const float* wf_en  = (const float*)d_in[10];
    const float* bf_en  = (const float*)d_in[11];
    const float* wl_en  = (const float*)d_in[12];
    const float* bl_en  = (const float*)d_in[13];
    const float* wr_en  = (const float*)d_in[14];
    const float* br_en  = (const float*)d_in[15];
    const int*   ee_ty  = (const int*)d_in[18];
    const int*   en_ty  = (const int*)d_in[21];

    double* kws = (double*)d_ws;       // [512] partial log-Jastrow from ee
    float*  out = (float*)d_out;       // [512]

    (void)hipFuncSetAttribute((const void*)ee_kernel,
            hipFuncAttributeMaxDynamicSharedMemorySize, EE_TOTAL*(int)sizeof(float));
    (void)hipFuncSetAttribute((const void*)en_kernel,
            hipFuncAttributeMaxDynamicSharedMemorySize, EN_TOTAL*(int)sizeof(float));

    ee_kernel<<<NB, BLOCK, EE_TOTAL*sizeof(float), stream>>>(
        pos, emb_ee, wf_ee, bf_ee, wl_ee, bl_ee, wr_ee, br_ee, ee_ty, kws);
    en_kernel<<<NB, BLOCK, EN_TOTAL*sizeof(float), stream>>>(
        pos, atoms, emb_en, wf_en, bf_en, wl_en, bl_en, wr_en, br_en, en_ty, kws, out);
}

// Round 3
// 216.225 us; speedup vs baseline: 1.5363x; 1.5363x over previous
//
#include <hip/hip_runtime.h>
#include <math.h>

#define NB      512
#define NELEC   30
#define NATOMS  10
#define NNEN    40      // en graph nodes: 30 electrons + 10 atoms
#define FEAT    64
#define KRBF    64
#define BLOCK   512
#define NWAVES  (BLOCK/64)
#define NPEE    435     // unique elec-elec pairs
#define NPEN    300     // unique elec-nuc pairs
#define TILE    32      // feature tile for filt LDS round-trip
#define TPAD    33      // tile row stride (+1): lanes hit banks (p+ff)%32, 2-way = free

// ---------------- LDS layouts (in floats) ----------------
// ee: xyz[96] | h[30*64] | agg[30*64] | fT[435*33]
#define EE_H     96
#define EE_AGG   (EE_H + NELEC*FEAT)
#define EE_FT    (EE_AGG + NELEC*FEAT)
#define EE_TOTAL (EE_FT + NPEE*TPAD)            // 18291 floats = 73164 B -> 2 blocks/CU
// en: xyz[96] | h[40*64] | agg[40*64] | fT[300*33]
#define EN_H     96
#define EN_AGG   (EN_H + NNEN*FEAT)
#define EN_FT    (EN_AGG + NNEN*FEAT)
#define EN_TOTAL (EN_FT + NPEN*TPAD)            // 15116 floats = 60464 B -> 2 blocks/CU

// triangular pair index base for row i (i<j pairs of 30 electrons)
__device__ __forceinline__ int ee_base(int i) { return 29*i - ((i*(i-1))>>1); }

// ==========================================================================
// elec-elec GNN: one block per batch. Writes partial log-Jastrow (double).
// filt lives in facc[64] VGPRs; ALL facc indexing is compile-time constant
// (l and t loops fully unrolled) so the array stays in registers — R2's
// runtime-t indexing demoted it to scratch (153 MB FETCH = spill traffic).
// FP op sequences bit-identical to the R1 passing kernel.
// ==========================================================================
__global__ __launch_bounds__(BLOCK, 4)
void ee_kernel(const float* __restrict__ pos,
               const float* __restrict__ emb,
               const float* __restrict__ wf,
               const float* __restrict__ bf,
               const float* __restrict__ wl,
               const float* __restrict__ bl,
               const float* __restrict__ wr,
               const float* __restrict__ br,
               const int*   __restrict__ types,
               double*      __restrict__ kout)
{
    extern __shared__ float sm[];
    float* xyz  = sm;           // [96]
    float* hS   = sm + EE_H;    // [30][64]
    float* aggS = sm + EE_AGG;  // [30][64]
    float* fT   = sm + EE_FT;   // [435][33] feature tile

    const int tid  = threadIdx.x;
    const int b    = blockIdx.x;
    const int lane = tid & 63;
    const int w    = tid >> 6;

    // stage positions; init h = emb[types]
    for (int idx = tid; idx < NELEC*3; idx += BLOCK) xyz[idx] = pos[b*NELEC*3 + idx];
    for (int idx = tid; idx < NELEC*FEAT; idx += BLOCK) {
        int n = idx >> 6, f = idx & 63;
        hS[idx] = emb[types[n]*FEAT + f];
    }
    __syncthreads();

    // ---- filter GEMM: one unique pair per lane (clamped -> uniform CF) ----
    const int p = (tid < NPEE) ? tid : (NPEE - 1);
    float facc[FEAT];
    {
        int i = 0, rem = p;
        while (rem >= NELEC - 1 - i) { rem -= NELEC - 1 - i; ++i; }
        const int j = i + 1 + rem;
        const float dx = xyz[3*i+0] - xyz[3*j+0];
        const float dy = xyz[3*i+1] - xyz[3*j+1];
        const float dz = xyz[3*i+2] - xyz[3*j+2];
        const float dd = sqrtf(dx*dx + dy*dy + dz*dz);

        #pragma unroll
        for (int f = 0; f < FEAT; ++f) facc[f] = bf[f];  // uniform -> s_load
        #pragma unroll 2
        for (int k = 0; k < KRBF; ++k) {
            const float ck = (float)((double)k * (8.0/63.0));
            const float t  = dd - ck;
            const float rk = expf(-t*t);
            const float* wrow = wf + k*FEAT;             // wave-uniform row
            #pragma unroll
            for (int f = 0; f < FEAT; ++f) facc[f] = fmaf(rk, wrow[f], facc[f]);
        }
        #pragma unroll
        for (int f = 0; f < FEAT; ++f) facc[f] = tanhf(facc[f]);
    }

    // ---- interaction layers (FULLY UNROLLED: static facc indices) ----
    #pragma unroll
    for (int l = 0; l < 2; ++l) {
        const float* wlL = wl + l*FEAT*FEAT;
        const float* blL = bl + l*FEAT;

        #pragma unroll
        for (int t = 0; t < 2; ++t) {
            __syncthreads();   // protect fT from previous tile's readers
            #pragma unroll
            for (int ff = 0; ff < TILE; ++ff)
                fT[p*TPAD + ff] = facc[t*TILE + ff];     // static index
            __syncthreads();

            // agg[i][t*32+ff] = sum_{j!=i, j asc} h[j][f] * filt[p(i,j)][f]
            #pragma unroll
            for (int pass = 0; pass < 2; ++pass) {
                const int idx = tid + pass*BLOCK;
                if (idx < NELEC*TILE) {
                    const int i  = idx >> 5;
                    const int ff = idx & 31;
                    const int f  = t*TILE + ff;
                    float a = 0.f;
                    #pragma unroll
                    for (int j = 0; j < NELEC; ++j) {
                        if (j != i) {
                            int pp = (j < i) ? (ee_base(j) + (i - j - 1))
                                             : (ee_base(i) + (j - i - 1));
                            a = fmaf(hS[j*FEAT + f], fT[pp*TPAD + ff], a);
                        }
                    }
                    aggS[i*FEAT + f] = a;
                }
            }
        }
        __syncthreads();

        // h += tanh(agg @ wl + bl)   (lane = feature, wave-strided nodes)
        for (int i = w; i < NELEC; i += NWAVES) {
            float a2 = 0.f;
            const float4* arow = reinterpret_cast<const float4*>(aggS + i*FEAT);
            #pragma unroll
            for (int k = 0; k < FEAT/4; ++k) {
                float4 av = arow[k];                      // broadcast b128
                a2 = fmaf(av.x, wlL[(4*k+0)*FEAT + lane], a2);
                a2 = fmaf(av.y, wlL[(4*k+1)*FEAT + lane], a2);
                a2 = fmaf(av.z, wlL[(4*k+2)*FEAT + lane], a2);
                a2 = fmaf(av.w, wlL[(4*k+3)*FEAT + lane], a2);
            }
            hS[i*FEAT + lane] += tanhf(a2 + blL[lane]);
        }
        __syncthreads();
    }

    // ---- readout: (sum_n h[n]) . wr + br   (f64 tail) ----
    if (w == 0) {
        float s = 0.f;
        #pragma unroll
        for (int n = 0; n < NELEC; ++n) s += hS[n*FEAT + lane];
        double dv = (double)s * (double)wr[lane];
        #pragma unroll
        for (int o = 32; o > 0; o >>= 1) dv += __shfl_xor(dv, o, 64);
        if (lane == 0) kout[b] = dv + (double)br[0];
    }
}

// ==========================================================================
// elec-nuc GNN + final combine: out[b] = exp(k_ee + k_en)
// ==========================================================================
__global__ __launch_bounds__(BLOCK, 4)
void en_kernel(const float* __restrict__ pos,
               const float* __restrict__ atoms,
               const float* __restrict__ emb,
               const float* __restrict__ wf,
               const float* __restrict__ bf,
               const float* __restrict__ wl,
               const float* __restrict__ bl,
               const float* __restrict__ wr,
               const float* __restrict__ br,
               const int*   __restrict__ types,
               const double* __restrict__ kin,
               float*       __restrict__ out)
{
    extern __shared__ float sm[];
    float* xyz  = sm;           // [96]
    float* hS   = sm + EN_H;    // [40][64]
    float* aggS = sm + EN_AGG;  // [40][64]
    float* fT   = sm + EN_FT;   // [300][33]

    const int tid  = threadIdx.x;
    const int b    = blockIdx.x;
    const int lane = tid & 63;
    const int w    = tid >> 6;

    for (int idx = tid; idx < NELEC*3; idx += BLOCK) xyz[idx] = pos[b*NELEC*3 + idx];
    for (int idx = tid; idx < NNEN*FEAT; idx += BLOCK) {
        int n = idx >> 6, f = idx & 63;
        hS[idx] = emb[types[n]*FEAT + f];
    }
    __syncthreads();

    // ---- filter GEMM: pair q = a*30 + e (atom-major, matches ref ordering) ----
    const int p = (tid < NPEN) ? tid : (NPEN - 1);
    float facc[FEAT];
    {
        const int a = p / NELEC;
        const int e = p - a*NELEC;
        const float dx = xyz[3*e+0] - atoms[3*a+0];
        const float dy = xyz[3*e+1] - atoms[3*a+1];
        const float dz = xyz[3*e+2] - atoms[3*a+2];
        const float dd = sqrtf(dx*dx + dy*dy + dz*dz);

        #pragma unroll
        for (int f = 0; f < FEAT; ++f) facc[f] = bf[f];
        #pragma unroll 2
        for (int k = 0; k < KRBF; ++k) {
            const float ck = (float)((double)k * (8.0/63.0));
            const float t  = dd - ck;
            const float rk = expf(-t*t);
            const float* wrow = wf + k*FEAT;
            #pragma unroll
            for (int f = 0; f < FEAT; ++f) facc[f] = fmaf(rk, wrow[f], facc[f]);
        }
        #pragma unroll
        for (int f = 0; f < FEAT; ++f) facc[f] = tanhf(facc[f]);
    }

    #pragma unroll
    for (int l = 0; l < 2; ++l) {
        const float* wlL = wl + l*FEAT*FEAT;
        const float* blL = bl + l*FEAT;

        #pragma unroll
        for (int t = 0; t < 2; ++t) {
            __syncthreads();
            #pragma unroll
            for (int ff = 0; ff < TILE; ++ff)
                fT[p*TPAD + ff] = facc[t*TILE + ff];     // static index
            __syncthreads();

            // bipartite messages: 40 nodes x 32 feats = 1280 items, 3 passes
            #pragma unroll
            for (int pass = 0; pass < 3; ++pass) {
                const int idx = tid + pass*BLOCK;
                if (idx < NNEN*TILE) {
                    const int n  = idx >> 5;
                    const int ff = idx & 31;
                    const int f  = t*TILE + ff;
                    float a = 0.f;
                    if (n < NELEC) {            // electron node: atoms ascending
                        #pragma unroll
                        for (int at = 0; at < NATOMS; ++at)
                            a = fmaf(hS[(NELEC+at)*FEAT + f],
                                     fT[(at*NELEC + n)*TPAD + ff], a);
                    } else {                    // atom node: electrons ascending
                        const int at = n - NELEC;
                        #pragma unroll
                        for (int e2 = 0; e2 < NELEC; ++e2)
                            a = fmaf(hS[e2*FEAT + f],
                                     fT[(at*NELEC + e2)*TPAD + ff], a);
                    }
                    aggS[n*FEAT + f] = a;
                }
            }
        }
        __syncthreads();

        for (int n = w; n < NNEN; n += NWAVES) {
            float a2 = 0.f;
            const float4* arow = reinterpret_cast<const float4*>(aggS + n*FEAT);
            #pragma unroll
            for (int k = 0; k < FEAT/4; ++k) {
                float4 av = arow[k];
                a2 = fmaf(av.x, wlL[(4*k+0)*FEAT + lane], a2);
                a2 = fmaf(av.y, wlL[(4*k+1)*FEAT + lane], a2);
                a2 = fmaf(av.z, wlL[(4*k+2)*FEAT + lane], a2);
                a2 = fmaf(av.w, wlL[(4*k+3)*FEAT + lane], a2);
            }
            hS[n*FEAT + lane] += tanhf(a2 + blL[lane]);
        }
        __syncthreads();
    }

    if (w == 0) {
        float s = 0.f;
        #pragma unroll
        for (int n = 0; n < NNEN; ++n) s += hS[n*FEAT + lane];
        double dv = (double)s * (double)wr[lane];
        #pragma unroll
        for (int o = 32; o > 0; o >>= 1) dv += __shfl_xor(dv, o, 64);
        if (lane == 0) out[b] = (float)exp(dv + (double)br[0] + kin[b]);
    }
}

// ==========================================================================
extern "C" void kernel_launch(void* const* d_in, const int* in_sizes, int n_in,
                              void* d_out, int out_size, void* d_ws, size_t ws_size,
                              hipStream_t stream) {
    const float* pos    = (const float*)d_in[0];
    const float* atoms  = (const float*)d_in[1];
    const float* emb_ee = (const float*)d_in[2];
    const float* wf_ee  = (const float*)d_in[3];
    const float* bf_ee  = (const float*)d_in[4];
    const float* wl_ee  = (const float*)d_in[5];
    const float* bl_ee  = (const float*)d_in[6];
    const float* wr_ee  = (const float*)d_in[7];
    const float* br_ee  = (const float*)d_in[8];
    const float* emb_en = (const float*)d_in[9];
    const float* wf_en  = (const float*)d_in[10];
    const float* bf_en  = (const float*)d_in[11];
    const float* wl_en  = (const float*)d_in[12];
    const float* bl_en  = (const float*)d_in[13];
    const float* wr_en  = (const float*)d_in[14];
    const float* br_en  = (const float*)d_in[15];
    const int*   ee_ty  = (const int*)d_in[18];
    const int*   en_ty  = (const int*)d_in[21];

    double* kws = (double*)d_ws;       // [512] partial log-Jastrow from ee
    float*  out = (float*)d_out;       // [512]

    (void)hipFuncSetAttribute((const void*)ee_kernel,
            hipFuncAttributeMaxDynamicSharedMemorySize, EE_TOTAL*(int)sizeof(float));
    (void)hipFuncSetAttribute((const void*)en_kernel,
            hipFuncAttributeMaxDynamicSharedMemorySize, EN_TOTAL*(int)sizeof(float));

    ee_kernel<<<NB, BLOCK, EE_TOTAL*sizeof(float), stream>>>(
        pos, emb_ee, wf_ee, bf_ee, wl_ee, bl_ee, wr_ee, br_ee, ee_ty, kws);
    en_kernel<<<NB, BLOCK, EN_TOTAL*sizeof(float), stream>>>(
        pos, atoms, emb_en, wf_en, bf_en, wl_en, bl_en, wr_en, br_en, en_ty, kws, out);
}